// Round 1
// baseline (144.722 us; speedup 1.0000x reference)
//
#include <hip/hip_runtime.h>
#include <math.h>

#define BB 4
#define NN 8192
#define KNB 16
#define DD 128
#define SS 17            // K+1 (self + neighbors)
#define M_TOT (BB*NN)    // 32768
#define WPAD 136         // padded inner stride (elems) for LDS tiles

typedef __attribute__((ext_vector_type(8))) short          bf8;
typedef __attribute__((ext_vector_type(4))) float          f4;
typedef __attribute__((ext_vector_type(4))) unsigned short u16x4;

static __device__ __forceinline__ unsigned short f2bf(float f) {
    unsigned u = __builtin_bit_cast(unsigned, f);
    u += 0x7fffu + ((u >> 16) & 1u);        // round-to-nearest-even
    return (unsigned short)(u >> 16);
}
static __device__ __forceinline__ float bf2f_s(short h) {
    return __builtin_bit_cast(float, (unsigned)(unsigned short)h << 16);
}

// ---------------------------------------------------------------------------
// Convert: six 128x128 fp32 weights -> bf16 W^T[n][k] (blocks 0..95), and
// X fp32 -> bf16 (blocks 96..4191). X-bf16 is read 3x by the split qkv grid.
// ---------------------------------------------------------------------------
__global__ __launch_bounds__(256) void cvt_kernel(
    const float* __restrict__ Wq, const float* __restrict__ Wk,
    const float* __restrict__ Wv, const float* __restrict__ Wo,
    const float* __restrict__ W1, const float* __restrict__ W2,
    const float* __restrict__ X,
    unsigned short* __restrict__ outW, unsigned short* __restrict__ Xbf)
{
    const int blk = blockIdx.x;
    if (blk < 96) {
        int m = blk >> 4;
        const float* src = (m == 0) ? Wq : (m == 1) ? Wk : (m == 2) ? Wv
                         : (m == 3) ? Wo : (m == 4) ? W1 : W2;
        unsigned short* dst = outW + m * 16384;
        int o = (blk & 15) * 1024 + threadIdx.x * 4;   // output idx [n][k]
        int n = o >> 7, k = o & 127;
        u16x4 r;
        #pragma unroll
        for (int i = 0; i < 4; ++i) r[i] = f2bf(src[(size_t)(k + i) * 128 + n]);
        *(u16x4*)(dst + o) = r;
    } else {
        int o = (blk - 96) * 1024 + threadIdx.x * 4;   // 0 .. 4194303
        float4 v = *(const float4*)(X + o);
        u16x4 r;
        r[0] = f2bf(v.x); r[1] = f2bf(v.y); r[2] = f2bf(v.z); r[3] = f2bf(v.w);
        *(u16x4*)(Xbf + o) = r;
    }
}

// ---------------------------------------------------------------------------
// QKV projection, split by output: block = (64 rows) x (one of Q/K/V).
// Grid 1536 (3 x 512): g = blk>>9 picks the weight; one GEMM, ONE barrier,
// no Wb reload. LDS 17.4 + 34.8 = 52.2 KB -> 3 blocks/CU (12 waves/CU vs 8
// before). Rows XCD-pinned: batch b -> XCD pair {2b,2b+1} so kh/vh writes
// stay in the L2 pair attn reads from (sub&7 tracks blockIdx%8 since the
// 512-block g-groups preserve low bits).
// Fragment maps (m89-verified): A[m=lane&15][k=quad*8+j],
// B[k=quad*8+j][n=lane&15], D[row=quad*4+r][col=lane&15].
// ---------------------------------------------------------------------------
__global__ __launch_bounds__(256) void qkv_kernel(
    const unsigned short* __restrict__ Xbf, const unsigned short* __restrict__ WtT,
    const float* __restrict__ bq, const float* __restrict__ bk,
    const float* __restrict__ bv,
    unsigned short* __restrict__ qh, unsigned short* __restrict__ kh,
    unsigned short* __restrict__ vh)
{
    __shared__ unsigned short Xs[64 * WPAD];    // 17408 B
    __shared__ unsigned short Wb[128 * WPAD];   // 34816 B

    const int tid = threadIdx.x;
    const int g   = blockIdx.x >> 9;            // 0=Q 1=K 2=V
    const int sub = blockIdx.x & 511;
    const int xcd = sub & 7;
    const int bb  = xcd >> 1;                   // batch pinned to XCD pair
    const int ii  = ((sub >> 3) << 1) | (xcd & 1);   // 0..127 within batch
    const int row0 = bb * NN + ii * 64;

    // Stage X tile (bf16, coalesced 16 B copies)
    {
        const bf8* Xg = (const bf8*)(Xbf + (size_t)row0 * DD);
        #pragma unroll
        for (int i = 0; i < 4; ++i) {
            int idx = tid + i * 256;            // 0..1023 chunks of 8 elems
            int r = idx >> 4, c8 = idx & 15;
            *(bf8*)(Xs + r * WPAD + c8 * 8) = Xg[idx];
        }
    }
    // Stage W^T[g]
    {
        const bf8* Wg = (const bf8*)(WtT + g * 16384);
        #pragma unroll
        for (int i = 0; i < 8; ++i) {
            int c = tid + i * 256;
            int n = c >> 4, k8 = c & 15;
            *(bf8*)(Wb + n * WPAD + k8 * 8) = Wg[c];
        }
    }
    __syncthreads();     // the only barrier

    const int lane = tid & 63, wv = tid >> 6;   // wave owns rows wv*16..+15
    const int ln = lane & 15, quad = lane >> 4;

    bf8 afr[4];
    #pragma unroll
    for (int s = 0; s < 4; ++s)
        afr[s] = *(const bf8*)(Xs + (wv * 16 + ln) * WPAD + s * 32 + quad * 8);

    f4 acc[8] = {};
    #pragma unroll
    for (int t = 0; t < 8; ++t) {
        bf8 bfr[4];
        #pragma unroll
        for (int s = 0; s < 4; ++s)
            bfr[s] = *(const bf8*)(Wb + (t * 16 + ln) * WPAD + s * 32 + quad * 8);
        #pragma unroll
        for (int s = 0; s < 4; ++s)
            acc[t] = __builtin_amdgcn_mfma_f32_16x16x32_bf16(afr[s], bfr[s], acc[t], 0, 0, 0);
    }

    const float* bias = (g == 0) ? bq : (g == 1) ? bk : bv;
    unsigned short* Y  = (g == 0) ? qh : (g == 1) ? kh : vh;
    #pragma unroll
    for (int t = 0; t < 8; ++t) {
        int col = t * 16 + ln;
        float bc = bias[col];
        #pragma unroll
        for (int r = 0; r < 4; ++r) {
            int row = row0 + wv * 16 + quad * 4 + r;
            Y[(size_t)row * DD + col] = f2bf(acc[t][r] + bc);
        }
    }
}

// ---------------------------------------------------------------------------
// Attention, register-resident. 16 lanes per vertex, lane owns 8 dims (16 B
// loads). Head = 4 lanes -> shfl_xor width 4. 16 vertices/block, 2048 blocks.
// XCD swizzle: batch b pinned to XCD pair {2b,2b+1}.
// NEW: exec-mask skip of K/V rows with s > len — valid_lens ~ U[0,16) means
// on average only 8.5/17 rows are needed -> ~2x fewer gather bytes. Loads are
// batched (9+8) into registers so guarded loads still pipeline.
// ---------------------------------------------------------------------------
__global__ __launch_bounds__(256) void attn_kernel(
    const unsigned short* __restrict__ Qh, const unsigned short* __restrict__ Kh,
    const unsigned short* __restrict__ Vh, const int* __restrict__ nbr,
    const int* __restrict__ vlen, unsigned short* __restrict__ Ctx)
{
    const int tid  = threadIdx.x;
    const int vloc = tid >> 4;        // 0..15
    const int ln   = tid & 15;        // 8-dim slot
    const int blk  = blockIdx.x;
    const int b    = (blk & 7) >> 1;                 // batch from XCD pair
    const int j    = ((blk >> 3) << 1) | (blk & 1);  // within-batch group 0..511
    const int v    = b * NN + j * 16 + vloc;

    const int len = vlen[v];          // rows 0..len are valid (len in [0,16))

    // q fragment: 8 dims
    bf8 q8 = *(const bf8*)(Qh + (size_t)v * DD + ln * 8);
    float qf[8];
    #pragma unroll
    for (int i = 0; i < 8; ++i) qf[i] = bf2f_s(q8[i]);

    int rows[SS];
    rows[0] = v;
    {
        const int4* np = (const int4*)(nbr + (size_t)v * KNB);
        #pragma unroll
        for (int i = 0; i < 4; ++i) {
            int4 n4 = np[i];
            rows[1 + i * 4 + 0] = b * NN + n4.x;
            rows[1 + i * 4 + 1] = b * NN + n4.y;
            rows[1 + i * 4 + 2] = b * NN + n4.z;
            rows[1 + i * 4 + 3] = b * NN + n4.w;
        }
    }

    float sc[SS];
    #pragma unroll
    for (int s = 0; s < SS; ++s) sc[s] = -1.0e9f;   // invalid slots stay -1e9

    // Pass 1: scores, only for valid s (lane's head = ln>>2).
    {
        bf8 kr[9];
        #pragma unroll
        for (int s = 0; s <= 8; ++s)
            if (s <= len) kr[s] = *(const bf8*)(Kh + (size_t)rows[s] * DD + ln * 8);
        #pragma unroll
        for (int s = 0; s <= 8; ++s)
            if (s <= len) {
                float p = 0.f;
                #pragma unroll
                for (int i = 0; i < 8; ++i) p = fmaf(qf[i], bf2f_s(kr[s][i]), p);
                p += __shfl_xor(p, 1, 4);
                p += __shfl_xor(p, 2, 4);
                sc[s] = p * 0.17677669529663687f;   // 1/sqrt(32)
            }
    }
    {
        bf8 kr[8];
        #pragma unroll
        for (int s = 9; s < SS; ++s)
            if (s <= len) kr[s - 9] = *(const bf8*)(Kh + (size_t)rows[s] * DD + ln * 8);
        #pragma unroll
        for (int s = 9; s < SS; ++s)
            if (s <= len) {
                float p = 0.f;
                #pragma unroll
                for (int i = 0; i < 8; ++i) p = fmaf(qf[i], bf2f_s(kr[s - 9][i]), p);
                p += __shfl_xor(p, 1, 4);
                p += __shfl_xor(p, 2, 4);
                sc[s] = p * 0.17677669529663687f;
            }
    }

    // Softmax, unguarded: invalid sc = -1e9 -> expf underflows to exactly 0.
    float m = sc[0];
    #pragma unroll
    for (int s = 1; s < SS; ++s) m = fmaxf(m, sc[s]);
    float sum = 0.f;
    #pragma unroll
    for (int s = 0; s < SS; ++s) {
        float e = __expf(sc[s] - m);
        sc[s] = e;
        sum += e;
    }
    const float inv = 1.f / sum;

    // Pass 2: weighted V accumulate, only for valid s.
    float acc[8] = {};
    {
        bf8 vr[9];
        #pragma unroll
        for (int s = 0; s <= 8; ++s)
            if (s <= len) vr[s] = *(const bf8*)(Vh + (size_t)rows[s] * DD + ln * 8);
        #pragma unroll
        for (int s = 0; s <= 8; ++s)
            if (s <= len) {
                float w = sc[s] * inv;
                #pragma unroll
                for (int i = 0; i < 8; ++i) acc[i] = fmaf(w, bf2f_s(vr[s][i]), acc[i]);
            }
    }
    {
        bf8 vr[8];
        #pragma unroll
        for (int s = 9; s < SS; ++s)
            if (s <= len) vr[s - 9] = *(const bf8*)(Vh + (size_t)rows[s] * DD + ln * 8);
        #pragma unroll
        for (int s = 9; s < SS; ++s)
            if (s <= len) {
                float w = sc[s] * inv;
                #pragma unroll
                for (int i = 0; i < 8; ++i) acc[i] = fmaf(w, bf2f_s(vr[s - 9][i]), acc[i]);
            }
    }

    bf8 r;
    #pragma unroll
    for (int i = 0; i < 8; ++i) r[i] = (short)f2bf(acc[i]);
    *(bf8*)(Ctx + (size_t)v * DD + ln * 8) = r;
}

// ---------------------------------------------------------------------------
// Fused Wo + FFN(W1,relu,W2): ctx -> out, chained through one LDS tile.
// 64 rows/block, 4 waves, wave tile 16x128. LDS 52.2 KB -> 3 blocks/CU.
// (Unchanged this round — sequential chain; attack next if dominant.)
// ---------------------------------------------------------------------------
__global__ __launch_bounds__(256) void ffn_kernel(
    const unsigned short* __restrict__ Ctxg, const unsigned short* __restrict__ WtT3,
    const float* __restrict__ bo, const float* __restrict__ b1,
    const float* __restrict__ b2, float* __restrict__ Out)
{
    __shared__ unsigned short Ct[64 * WPAD];
    __shared__ unsigned short Wb[128 * WPAD];

    const int tid  = threadIdx.x;
    const int row0 = blockIdx.x * 64;

    {
        const bf8* Cg = (const bf8*)(Ctxg + (size_t)row0 * DD);
        #pragma unroll
        for (int i = 0; i < 4; ++i) {
            int idx = tid + i * 256;
            int r = idx >> 4, c8 = idx & 15;
            *(bf8*)(Ct + r * WPAD + c8 * 8) = Cg[idx];
        }
    }
    #pragma unroll
    for (int i = 0; i < 8; ++i) {
        int c = tid + i * 256;
        int n = c >> 4, k8 = c & 15;
        *(bf8*)(Wb + n * WPAD + k8 * 8) = ((const bf8*)WtT3)[c];
    }

    const int lane = tid & 63, wv = tid >> 6;
    const int ln = lane & 15, quad = lane >> 4;
    const float* biases[3] = { bo, b1, b2 };
    __syncthreads();

    #pragma unroll 1
    for (int g = 0; g < 3; ++g) {
        bf8 afr[4];
        #pragma unroll
        for (int s = 0; s < 4; ++s)
            afr[s] = *(const bf8*)(Ct + (wv * 16 + ln) * WPAD + s * 32 + quad * 8);

        f4 acc[8] = {};
        #pragma unroll
        for (int t = 0; t < 8; ++t) {
            bf8 bfr[4];
            #pragma unroll
            for (int s = 0; s < 4; ++s)
                bfr[s] = *(const bf8*)(Wb + (t * 16 + ln) * WPAD + s * 32 + quad * 8);
            #pragma unroll
            for (int s = 0; s < 4; ++s)
                acc[t] = __builtin_amdgcn_mfma_f32_16x16x32_bf16(afr[s], bfr[s], acc[t], 0, 0, 0);
        }

        __syncthreads();   // everyone done reading Ct & Wb

        const float* bias = biases[g];
        if (g == 2) {
            #pragma unroll
            for (int t = 0; t < 8; ++t) {
                int col = t * 16 + ln;
                float bc = bias[col];
                #pragma unroll
                for (int r = 0; r < 4; ++r) {
                    int row = row0 + wv * 16 + quad * 4 + r;
                    Out[(size_t)row * DD + col] = acc[t][r] + bc;
                }
            }
        } else {
            const bf8* Wn = (const bf8*)(WtT3 + (g + 1) * 16384);
            #pragma unroll
            for (int i = 0; i < 8; ++i) {
                int c = tid + i * 256;
                int n = c >> 4, k8 = c & 15;
                *(bf8*)(Wb + n * WPAD + k8 * 8) = Wn[c];
            }
            #pragma unroll
            for (int t = 0; t < 8; ++t) {
                int col = t * 16 + ln;
                float bc = bias[col];
                #pragma unroll
                for (int r = 0; r < 4; ++r) {
                    int rloc = wv * 16 + quad * 4 + r;
                    float vv = acc[t][r] + bc;
                    if (g == 1) vv = fmaxf(vv, 0.f);
                    Ct[rloc * WPAD + col] = f2bf(vv);
                }
            }
            __syncthreads();
        }
    }
}

// ---------------------------------------------------------------------------
extern "C" void kernel_launch(void* const* d_in, const int* in_sizes, int n_in,
                              void* d_out, int out_size, void* d_ws, size_t ws_size,
                              hipStream_t stream)
{
    const float* vf   = (const float*)d_in[0];
    const int*   nbr  = (const int*)  d_in[1];
    const int*   vlen = (const int*)  d_in[2];
    const float* Wq   = (const float*)d_in[3];
    const float* bq   = (const float*)d_in[4];
    const float* Wk   = (const float*)d_in[5];
    const float* bk   = (const float*)d_in[6];
    const float* Wv   = (const float*)d_in[7];
    const float* bv   = (const float*)d_in[8];
    const float* Wo   = (const float*)d_in[9];
    const float* bo   = (const float*)d_in[10];
    const float* W1   = (const float*)d_in[11];
    const float* b1   = (const float*)d_in[12];
    const float* W2   = (const float*)d_in[13];
    const float* b2   = (const float*)d_in[14];

    float* out = (float*)d_out;

    const size_t SZ = (size_t)M_TOT * DD;
    unsigned short* WtT = (unsigned short*)d_ws;    // 6 x 16384 bf16
    unsigned short* qh  = WtT + 6 * 16384;
    unsigned short* kh  = qh + SZ;
    unsigned short* vh  = kh + SZ;
    unsigned short* ctx = vh + SZ;
    unsigned short* Xbf = ctx + SZ;                 // bf16 copy of vertex_feat

    cvt_kernel<<<96 + 4096, 256, 0, stream>>>(Wq, Wk, Wv, Wo, W1, W2, vf, WtT, Xbf);

    qkv_kernel<<<3 * (M_TOT / 64), 256, 0, stream>>>(Xbf, WtT, bq, bk, bv, qh, kh, vh);

    attn_kernel<<<M_TOT / 16, 256, 0, stream>>>(qh, kh, vh, nbr, vlen, ctx);

    ffn_kernel<<<M_TOT / 64, 256, 0, stream>>>(ctx, WtT + 3 * 16384, bo, b1, b2, out);
}